// Round 11
// baseline (956.718 us; speedup 1.0000x reference)
//
#include <hip/hip_runtime.h>
#include <hip/hip_fp16.h>

// N = 100000 nodes, E = 1600000 edges, IN=128, HID=128, LAT=64
// edge_index arrives on device as int32 (harness converts integer inputs).
//
// R10 + structural gather change: dedicated channel-TILED gather kernel.
// 8 tiles x 16 ch; per tile the fp16 feature slice is 3.2 MB -> L2-resident
// per XCD (tile-major grid), so E random 32B reads become L2 hits instead of
// L3 misses. Gather output msg: fp16, tiled [8][N][16], in ws. Dense kernels
// stage ms from msg (no in-kernel gather). CSR build / dec as R10.

__device__ __forceinline__ unsigned h2u(__half2 h) { union { __half2 h; unsigned u; } c; c.h = h; return c.u; }
__device__ __forceinline__ __half2 u2h(unsigned u) { union { unsigned u; __half2 h; } c; c.u = u; return c.h; }

// ---------------- f32 -> fp16 convert (x4) ----------------
__global__ void k_cvt(const float* __restrict__ in, unsigned* __restrict__ ob, int n4) {
    int i = blockIdx.x * blockDim.x + threadIdx.x;
    if (i < n4) {
        float4 v = ((const float4*)in)[i];
        uint2 o;
        o.x = h2u(__floats2half2_rn(v.x, v.y));
        o.y = h2u(__floats2half2_rn(v.z, v.w));
        ((uint2*)ob)[i] = o;
    }
}

// ---------------- merged weight transposes: Wt[k][c] = W[c][k] ----------------
__global__ void k_tw5(const float* __restrict__ W1l, const float* __restrict__ W1r,
                      const float* __restrict__ W2l, const float* __restrict__ W2r,
                      const float* __restrict__ Wdec,
                      float* __restrict__ wt1l, float* __restrict__ wt1r,
                      float* __restrict__ wt2l, float* __restrict__ wt2r,
                      float* __restrict__ wtdec) {
    int i = blockIdx.x * blockDim.x + threadIdx.x;   // 0 .. 57343
    const float* W; float* Wt; int K, OC, j;
    if (i < 16384)      { W = W1l;  Wt = wt1l;  K = 128; OC = 128; j = i; }
    else if (i < 32768) { W = W1r;  Wt = wt1r;  K = 128; OC = 128; j = i - 16384; }
    else if (i < 40960) { W = W2l;  Wt = wt2l;  K = 128; OC = 64;  j = i - 32768; }
    else if (i < 49152) { W = W2r;  Wt = wt2r;  K = 128; OC = 64;  j = i - 40960; }
    else if (i < 57344) { W = Wdec; Wt = wtdec; K = 64;  OC = 128; j = i - 49152; }
    else return;
    int k = j / OC, c = j % OC;
    Wt[j] = W[c * K + k];
}

// ---------------- degree (int): deg[dst]++ ----------------
__global__ void k_deg(const int* __restrict__ dst, int* __restrict__ deg, int E, int nNodes) {
    int i = blockIdx.x * blockDim.x + threadIdx.x;
    if (i < E) {
        unsigned d = (unsigned)dst[i];
        if (d < (unsigned)nNodes) atomicAdd(&deg[d], 1);
    }
}

// ---------------- scan stage 1 ----------------
__global__ void k_scan1(const int* __restrict__ deg, int* __restrict__ off,
                        int* __restrict__ bs, int nNodes) {
    __shared__ int tmp[256];
    int t = threadIdx.x;
    int i = blockIdx.x * 256 + t;
    int v = (i < nNodes) ? deg[i] : 0;
    tmp[t] = v;
    __syncthreads();
    for (int d = 1; d < 256; d <<= 1) {
        int add = (t >= d) ? tmp[t - d] : 0;
        __syncthreads();
        tmp[t] += add;
        __syncthreads();
    }
    if (i < nNodes) off[i] = tmp[t] - v;
    if (t == 255) bs[blockIdx.x] = tmp[255];
}

// ---------------- scan stage 2 (1 block) ----------------
__global__ void k_scan2(int* __restrict__ bs, int nb) {
    __shared__ int tmp[512];
    int t = threadIdx.x;
    int carry = 0;
    for (int start = 0; start < nb; start += 512) {
        int i = start + t;
        int v = (i < nb) ? bs[i] : 0;
        tmp[t] = v;
        __syncthreads();
        for (int d = 1; d < 512; d <<= 1) {
            int add = (t >= d) ? tmp[t - d] : 0;
            __syncthreads();
            tmp[t] += add;
            __syncthreads();
        }
        int incl = tmp[t];
        if (i < nb) bs[i] = incl - v + carry;
        int total = tmp[511];
        __syncthreads();
        carry += total;
    }
}

// ---------------- scan stage 3 ----------------
__global__ void k_scan3(int* __restrict__ off, const int* __restrict__ bs, int nNodes) {
    int i = blockIdx.x * 256 + threadIdx.x;
    if (i < nNodes) off[i] += bs[blockIdx.x];
}

// ---------------- CSR fill ----------------
__global__ void k_fill(const int* __restrict__ src, const int* __restrict__ dst,
                       const int* __restrict__ off, int* __restrict__ cur,
                       int* __restrict__ adj, int E, int nNodes) {
    int i = blockIdx.x * blockDim.x + threadIdx.x;
    if (i < E) {
        unsigned d = (unsigned)dst[i];
        unsigned s = (unsigned)src[i];
        if (d < (unsigned)nNodes && s < (unsigned)nNodes) {
            int pos = atomicAdd(&cur[d], 1);
            adj[off[d] + pos] = (int)s;
        }
    }
}

// ---------------- tiled gather-mean ----------------
// msg layout: [8 tiles][N][16 ch] fp16. Grid tile-major: all blocks of tile t
// run together -> the N x 16ch fp16 slice (3.2 MB) stays L2-resident per XCD.
// One thread per node: f32 accumulate of 16 ch, x4-unrolled neighbor loop.
#define ACC8(A, O, U)                                                     \
    {                                                                     \
        float2 t0 = __half22float2(u2h((U).x));                           \
        float2 t1 = __half22float2(u2h((U).y));                           \
        float2 t2 = __half22float2(u2h((U).z));                           \
        float2 t3 = __half22float2(u2h((U).w));                           \
        A[O+0] += t0.x; A[O+1] += t0.y; A[O+2] += t1.x; A[O+3] += t1.y;   \
        A[O+4] += t2.x; A[O+5] += t2.y; A[O+6] += t3.x; A[O+7] += t3.y;   \
    }

__launch_bounds__(256)
__global__ void k_gath(const unsigned short* __restrict__ feat,   // fp16 [N][128]
                       const int* __restrict__ adj, const int* __restrict__ off,
                       const int* __restrict__ deg,
                       unsigned short* __restrict__ msg,           // fp16 [8][N][16]
                       int nNodes, int nb) {
    int t = blockIdx.x / nb;                       // tile 0..7
    int n = (blockIdx.x - t * nb) * 256 + threadIdx.x;
    if (n >= nNodes) return;
    int o0 = off[n], dg = deg[n];
    int o1 = o0 + dg;
    float a[16];
#pragma unroll
    for (int j = 0; j < 16; ++j) a[j] = 0.f;
    const uint4* f4 = (const uint4*)feat;          // row = 16 uint4; tile t -> granules 2t,2t+1
    const int tg = t * 2;

    int k = o0;
    for (; k + 3 < o1; k += 4) {
        int s0 = adj[k], s1 = adj[k + 1], s2 = adj[k + 2], s3 = adj[k + 3];
        uint4 p0 = f4[(long long)s0 * 16 + tg], q0 = f4[(long long)s0 * 16 + tg + 1];
        uint4 p1 = f4[(long long)s1 * 16 + tg], q1 = f4[(long long)s1 * 16 + tg + 1];
        uint4 p2 = f4[(long long)s2 * 16 + tg], q2 = f4[(long long)s2 * 16 + tg + 1];
        uint4 p3 = f4[(long long)s3 * 16 + tg], q3 = f4[(long long)s3 * 16 + tg + 1];
        ACC8(a, 0, p0) ACC8(a, 8, q0)
        ACC8(a, 0, p1) ACC8(a, 8, q1)
        ACC8(a, 0, p2) ACC8(a, 8, q2)
        ACC8(a, 0, p3) ACC8(a, 8, q3)
    }
    for (; k < o1; ++k) {
        int s = adj[k];
        uint4 p = f4[(long long)s * 16 + tg], q = f4[(long long)s * 16 + tg + 1];
        ACC8(a, 0, p) ACC8(a, 8, q)
    }
    float inv = 1.f / fmaxf((float)dg, 1.f);
    uint4 st0, st1;
    st0.x = h2u(__floats2half2_rn(a[0] * inv,  a[1] * inv));
    st0.y = h2u(__floats2half2_rn(a[2] * inv,  a[3] * inv));
    st0.z = h2u(__floats2half2_rn(a[4] * inv,  a[5] * inv));
    st0.w = h2u(__floats2half2_rn(a[6] * inv,  a[7] * inv));
    st1.x = h2u(__floats2half2_rn(a[8] * inv,  a[9] * inv));
    st1.y = h2u(__floats2half2_rn(a[10] * inv, a[11] * inv));
    st1.z = h2u(__floats2half2_rn(a[12] * inv, a[13] * inv));
    st1.w = h2u(__floats2half2_rn(a[14] * inv, a[15] * inv));
    uint4* mp = (uint4*)msg + ((long long)t * nNodes + n) * 2;
    mp[0] = st0;
    mp[1] = st1;
}

// per-j FMA step macro: J = k within granule, COMP = float4 component
#define SAGE_STEP(J, COMP, WR4, WL4, RSTRIDE)                             \
    {                                                                     \
        float4 wr4 = WR4[(kc * 4 + J) * RSTRIDE + cg];                    \
        float4 wl4 = WL4[(kc * 4 + J) * RSTRIDE + cg];                    \
        _Pragma("unroll")                                                 \
        for (int rr = 0; rr < NROWS; ++rr) {                              \
            float xvj = xv[rr].COMP, mvj = mv[rr].COMP;                   \
            acc[rr][0] += xvj * wr4.x + mvj * wl4.x;                      \
            acc[rr][1] += xvj * wr4.y + mvj * wl4.y;                      \
            acc[rr][2] += xvj * wr4.z + mvj * wl4.z;                      \
            acc[rr][3] += xvj * wr4.w + mvj * wl4.w;                      \
        }                                                                 \
    }

// stage ms[32][PITCH] from tiled fp16 msg (coalesced uint4 reads)
#define STAGE_MS(PITCH)                                                   \
    for (int i = tid; i < 512; i += 256) {                                \
        int t = i >> 6, j = i & 63;                                       \
        int row = j >> 1, c = j & 1;                                      \
        int n = base + row;                                               \
        uint4 v = make_uint4(0u, 0u, 0u, 0u);                             \
        if (n < nNodes) v = ((const uint4*)msg)[((long long)t * nNodes + n) * 2 + c]; \
        float2 f0 = __half22float2(u2h(v.x)), f1 = __half22float2(u2h(v.y)); \
        float2 f2 = __half22float2(u2h(v.z)), f3 = __half22float2(u2h(v.w)); \
        ((float4*)&ms[row][0])[t * 4 + c * 2 + 0] = make_float4(f0.x, f0.y, f1.x, f1.y); \
        ((float4*)&ms[row][0])[t * 4 + c * 2 + 1] = make_float4(f2.x, f2.y, f3.x, f3.y); \
    }

// ---------------- SAGE layer 1 dense: h = relu(ms@Wl^T + b + x@Wr^T) ----------------
__launch_bounds__(256)
__global__ void k_sage1(const float* __restrict__ x, const unsigned short* __restrict__ msg,
                        const float* __restrict__ Wtl, const float* __restrict__ bl,
                        const float* __restrict__ Wtr,
                        unsigned* __restrict__ hb, int nNodes) {
    __shared__ float xs[32][128];
    __shared__ float ms[32][128];
    int tid = threadIdx.x;
    int base = blockIdx.x * 32;

    for (int i = tid; i < 32 * 32; i += 256) {
        int row = i >> 5, col4 = i & 31;
        int n = base + row;
        float4 xv = make_float4(0.f, 0.f, 0.f, 0.f);
        if (n < nNodes) xv = ((const float4*)x)[(long long)n * 32 + col4];
        ((float4*)&xs[row][0])[col4] = xv;
    }
    STAGE_MS(128)
    __syncthreads();

    const int NROWS = 4;
    int cg = tid & 31;
    int rg = tid >> 5;
    float acc[4][4];
#pragma unroll
    for (int rr = 0; rr < 4; ++rr)
#pragma unroll
        for (int cc = 0; cc < 4; ++cc) acc[rr][cc] = 0.f;

    const float4* WtR4 = (const float4*)Wtr;
    const float4* WtL4 = (const float4*)Wtl;

    for (int kc = 0; kc < 32; ++kc) {
        float4 xv[4], mv[4];
#pragma unroll
        for (int rr = 0; rr < 4; ++rr) {
            xv[rr] = ((const float4*)&xs[rg * 4 + rr][0])[kc];
            mv[rr] = ((const float4*)&ms[rg * 4 + rr][0])[kc];
        }
        SAGE_STEP(0, x, WtR4, WtL4, 32)
        SAGE_STEP(1, y, WtR4, WtL4, 32)
        SAGE_STEP(2, z, WtR4, WtL4, 32)
        SAGE_STEP(3, w, WtR4, WtL4, 32)
    }

    float4 b4 = ((const float4*)bl)[cg];
#pragma unroll
    for (int rr = 0; rr < 4; ++rr) {
        int n = base + rg * 4 + rr;
        if (n < nNodes) {
            float r0 = fmaxf(acc[rr][0] + b4.x, 0.f);
            float r1 = fmaxf(acc[rr][1] + b4.y, 0.f);
            float r2 = fmaxf(acc[rr][2] + b4.z, 0.f);
            float r3 = fmaxf(acc[rr][3] + b4.w, 0.f);
            uint2 st;
            st.x = h2u(__floats2half2_rn(r0, r1));
            st.y = h2u(__floats2half2_rn(r2, r3));
            ((uint2*)hb)[(long long)n * 32 + cg] = st;
        }
    }
}

// ---------------- SAGE layer 2 dense (64 out ch, no relu) ----------------
__launch_bounds__(256)
__global__ void k_sage2(const unsigned short* __restrict__ hb,
                        const unsigned short* __restrict__ msg,
                        const float* __restrict__ Wtl, const float* __restrict__ bl,
                        const float* __restrict__ Wtr,
                        float* __restrict__ z, int nNodes) {
    __shared__ float xs[32][132];
    __shared__ float ms[32][132];
    int tid = threadIdx.x;
    int base = blockIdx.x * 32;

    for (int i = tid; i < 32 * 32; i += 256) {
        int row = i >> 5, col4 = i & 31;
        int n = base + row;
        float4 xv = make_float4(0.f, 0.f, 0.f, 0.f);
        if (n < nNodes) {
            uint2 v = ((const uint2*)hb)[(long long)n * 32 + col4];
            float2 f0 = __half22float2(u2h(v.x));
            float2 f1 = __half22float2(u2h(v.y));
            xv = make_float4(f0.x, f0.y, f1.x, f1.y);
        }
        ((float4*)&xs[row][0])[col4] = xv;
    }
    STAGE_MS(132)
    __syncthreads();

    const int NROWS = 2;
    int cg = tid & 15;
    int rg = tid >> 4;
    float acc[2][4];
#pragma unroll
    for (int rr = 0; rr < 2; ++rr)
#pragma unroll
        for (int cc = 0; cc < 4; ++cc) acc[rr][cc] = 0.f;

    const float4* WtR4 = (const float4*)Wtr;
    const float4* WtL4 = (const float4*)Wtl;

    for (int kc = 0; kc < 32; ++kc) {
        float4 xv[2], mv[2];
#pragma unroll
        for (int rr = 0; rr < 2; ++rr) {
            xv[rr] = ((const float4*)&xs[rg * 2 + rr][0])[kc];
            mv[rr] = ((const float4*)&ms[rg * 2 + rr][0])[kc];
        }
        SAGE_STEP(0, x, WtR4, WtL4, 16)
        SAGE_STEP(1, y, WtR4, WtL4, 16)
        SAGE_STEP(2, z, WtR4, WtL4, 16)
        SAGE_STEP(3, w, WtR4, WtL4, 16)
    }

    float4 b4 = ((const float4*)bl)[cg];
#pragma unroll
    for (int rr = 0; rr < 2; ++rr) {
        int n = base + rg * 2 + rr;
        if (n < nNodes) {
            float4 o;
            o.x = acc[rr][0] + b4.x;
            o.y = acc[rr][1] + b4.y;
            o.z = acc[rr][2] + b4.z;
            o.w = acc[rr][3] + b4.w;
            ((float4*)z)[(long long)n * 16 + cg] = o;
        }
    }
}

// ---------------- decoder: out = z @ W_dec^T + b_dec (R10 verbatim) ----------------
__launch_bounds__(256)
__global__ void k_dec(const float* __restrict__ z, const float* __restrict__ Wt,
                      const float* __restrict__ b,
                      float* __restrict__ out, int nNodes) {
    __shared__ float zs[32][64];
    int tid = threadIdx.x;
    int base = blockIdx.x * 32;

    for (int i = tid; i < 32 * 16; i += 256) {
        int row = i >> 4, col4 = i & 15;
        int n = base + row;
        float4 zv = make_float4(0.f, 0.f, 0.f, 0.f);
        if (n < nNodes) zv = ((const float4*)z)[(long long)n * 16 + col4];
        ((float4*)&zs[row][0])[col4] = zv;
    }
    __syncthreads();

    int cg = tid & 31;
    int rg = tid >> 5;
    float acc[4][4];
#pragma unroll
    for (int rr = 0; rr < 4; ++rr)
#pragma unroll
        for (int cc = 0; cc < 4; ++cc) acc[rr][cc] = 0.f;

    const float4* Wt4 = (const float4*)Wt;

    for (int kc = 0; kc < 16; ++kc) {
        float4 zv[4];
#pragma unroll
        for (int rr = 0; rr < 4; ++rr)
            zv[rr] = ((const float4*)&zs[rg * 4 + rr][0])[kc];
#define DEC_STEP(J, COMP)                                                  \
        {                                                                  \
            float4 w4 = Wt4[(kc * 4 + J) * 32 + cg];                       \
            _Pragma("unroll")                                              \
            for (int rr = 0; rr < 4; ++rr) {                               \
                float zj = zv[rr].COMP;                                    \
                acc[rr][0] += zj * w4.x;                                   \
                acc[rr][1] += zj * w4.y;                                   \
                acc[rr][2] += zj * w4.z;                                   \
                acc[rr][3] += zj * w4.w;                                   \
            }                                                              \
        }
        DEC_STEP(0, x)
        DEC_STEP(1, y)
        DEC_STEP(2, z)
        DEC_STEP(3, w)
#undef DEC_STEP
    }

    float4 b4 = ((const float4*)b)[cg];
#pragma unroll
    for (int rr = 0; rr < 4; ++rr) {
        int n = base + rg * 4 + rr;
        if (n < nNodes) {
            float4 o;
            o.x = acc[rr][0] + b4.x;
            o.y = acc[rr][1] + b4.y;
            o.z = acc[rr][2] + b4.z;
            o.w = acc[rr][3] + b4.w;
            ((float4*)out)[(long long)n * 32 + cg] = o;
        }
    }
}

extern "C" void kernel_launch(void* const* d_in, const int* in_sizes, int n_in,
                              void* d_out, int out_size, void* d_ws, size_t ws_size,
                              hipStream_t stream) {
    const float* x    = (const float*)d_in[0];
    const int*   ei   = (const int*)d_in[1];   // int32 on device
    const float* W1l  = (const float*)d_in[2];
    const float* b1l  = (const float*)d_in[3];
    const float* W1r  = (const float*)d_in[4];
    const float* W2l  = (const float*)d_in[5];
    const float* b2l  = (const float*)d_in[6];
    const float* W2r  = (const float*)d_in[7];
    const float* Wdec = (const float*)d_in[8];
    const float* bdec = (const float*)d_in[9];

    const int N = in_sizes[0] / 128;
    const int E = in_sizes[1] / 2;
    const int nb = (N + 255) / 256;

    const int* src = ei;
    const int* dst = ei + E;

    // ws: [float Wt: wt1l 16384 | wt1r 16384 | wt2l 8192 | wt2r 8192 | wtdec 8192]
    //     [int: adj E | deg N | cur N | off N | bs nb]
    //     [fp16 msg: 8 * N * 16]
    float* wsf   = (float*)d_ws;
    float* wt1l  = wsf;
    float* wt1r  = wt1l + 16384;
    float* wt2l  = wt1r + 16384;
    float* wt2r  = wt2l + 8192;
    float* wtdec = wt2r + 8192;
    int*   adj   = (int*)(wtdec + 8192);
    int*   deg   = adj + E;
    int*   cur   = deg + N;
    int*   off   = cur + N;
    int*   bs    = off + N;
    unsigned short* msg = (unsigned short*)(bs + nb);
    // align msg to 16B
    msg = (unsigned short*)(((size_t)msg + 15) & ~(size_t)15);

    // d_out: x_recon [N*128 f32] | z [N*64 f32]. fp16 tensors in x_recon region:
    //   xh = fp16(x): first N*64 floats; hb = fp16(h): next N*64 floats.
    float*          outp = (float*)d_out;
    float*          z    = outp + (long long)N * 128;
    float*          xrec = outp;
    unsigned short* xh   = (unsigned short*)outp;
    unsigned*       hbW  = (unsigned*)(outp + (long long)N * 64);
    unsigned short* hb   = (unsigned short*)hbW;

    // weight transposes (merged) + x -> fp16
    k_tw5<<<(57344 + 255) / 256, 256, 0, stream>>>(W1l, W1r, W2l, W2r, Wdec,
                                                   wt1l, wt1r, wt2l, wt2r, wtdec);
    k_cvt<<<(N * 32 + 255) / 256, 256, 0, stream>>>(x, (unsigned*)xh, N * 32);

    hipMemsetAsync(deg, 0, (size_t)2 * N * sizeof(int), stream);

    k_deg  <<<(E + 255) / 256, 256, 0, stream>>>(dst, deg, E, N);
    k_scan1<<<nb, 256, 0, stream>>>(deg, off, bs, N);
    k_scan2<<<1, 512, 0, stream>>>(bs, nb);
    k_scan3<<<nb, 256, 0, stream>>>(off, bs, N);
    k_fill <<<(E + 255) / 256, 256, 0, stream>>>(src, dst, off, cur, adj, E, N);

    const int nblk = (N + 31) / 32;

    // layer 1: tiled gather (xh -> msg), dense (x, msg -> hb)
    k_gath <<<8 * nb, 256, 0, stream>>>(xh, adj, off, deg, msg, N, nb);
    k_sage1<<<nblk, 256, 0, stream>>>(x, msg, wt1l, b1l, wt1r, hbW, N);

    // layer 2: tiled gather (hb -> msg), dense (hb, msg -> z)
    k_gath <<<8 * nb, 256, 0, stream>>>(hb, adj, off, deg, msg, N, nb);
    k_sage2<<<nblk, 256, 0, stream>>>(hb, msg, wt2l, b2l, wt2r, z, N);

    k_dec  <<<nblk, 256, 0, stream>>>(z, wtdec, bdec, xrec, N);
}

// Round 13
// 914.636 us; speedup vs baseline: 1.0460x; 1.0460x over previous
//
#include <hip/hip_runtime.h>
#include <hip/hip_fp16.h>

// N = 100000 nodes, E = 1600000 edges, IN=128, HID=128, LAT=64
// edge_index arrives on device as int32 (harness converts integer inputs).
//
// R12 with compile fix (scalar nontemporal stores). Tile-CONTIGUOUS fp16
// feature layout [8][N][16], ONE KERNEL LAUNCH PER TILE (3.2 MB slice
// L2-resident per XCD), nontemporal adj loads / msg stores, 2 threads/node.

__device__ __forceinline__ unsigned h2u(__half2 h) { union { __half2 h; unsigned u; } c; c.h = h; return c.u; }
__device__ __forceinline__ __half2 u2h(unsigned u) { union { unsigned u; __half2 h; } c; c.u = u; return c.h; }

// ---------------- f32 x -> fp16 TILED xt[8][N][16] ----------------
__launch_bounds__(256)
__global__ void k_cvt_t(const float* __restrict__ x, unsigned short* __restrict__ xt,
                        int nNodes) {
    __shared__ float xs[32][128];
    int tid = threadIdx.x;
    int base = blockIdx.x * 32;
    for (int i = tid; i < 1024; i += 256) {
        int row = i >> 5, col4 = i & 31;
        int n = base + row;
        float4 v = make_float4(0.f, 0.f, 0.f, 0.f);
        if (n < nNodes) v = ((const float4*)x)[(long long)n * 32 + col4];
        ((float4*)&xs[row][0])[col4] = v;
    }
    __syncthreads();
    for (int j = tid; j < 512; j += 256) {
        int t = j >> 6, k = j & 63, row = k >> 1, c = k & 1;   // c: which uint4 (8 ch)
        int n = base + row;
        if (n < nNodes) {
            const float* p = &xs[row][16 * t + 8 * c];
            uint4 st;
            st.x = h2u(__floats2half2_rn(p[0], p[1]));
            st.y = h2u(__floats2half2_rn(p[2], p[3]));
            st.z = h2u(__floats2half2_rn(p[4], p[5]));
            st.w = h2u(__floats2half2_rn(p[6], p[7]));
            ((uint4*)xt)[((long long)t * nNodes + n) * 2 + c] = st;
        }
    }
}

// ---------------- merged weight transposes: Wt[k][c] = W[c][k] ----------------
__global__ void k_tw5(const float* __restrict__ W1l, const float* __restrict__ W1r,
                      const float* __restrict__ W2l, const float* __restrict__ W2r,
                      const float* __restrict__ Wdec,
                      float* __restrict__ wt1l, float* __restrict__ wt1r,
                      float* __restrict__ wt2l, float* __restrict__ wt2r,
                      float* __restrict__ wtdec) {
    int i = blockIdx.x * blockDim.x + threadIdx.x;   // 0 .. 57343
    const float* W; float* Wt; int K, OC, j;
    if (i < 16384)      { W = W1l;  Wt = wt1l;  K = 128; OC = 128; j = i; }
    else if (i < 32768) { W = W1r;  Wt = wt1r;  K = 128; OC = 128; j = i - 16384; }
    else if (i < 40960) { W = W2l;  Wt = wt2l;  K = 128; OC = 64;  j = i - 32768; }
    else if (i < 49152) { W = W2r;  Wt = wt2r;  K = 128; OC = 64;  j = i - 40960; }
    else if (i < 57344) { W = Wdec; Wt = wtdec; K = 64;  OC = 128; j = i - 49152; }
    else return;
    int k = j / OC, c = j % OC;
    Wt[j] = W[c * K + k];
}

// ---------------- degree (int): deg[dst]++ ----------------
__global__ void k_deg(const int* __restrict__ dst, int* __restrict__ deg, int E, int nNodes) {
    int i = blockIdx.x * blockDim.x + threadIdx.x;
    if (i < E) {
        unsigned d = (unsigned)dst[i];
        if (d < (unsigned)nNodes) atomicAdd(&deg[d], 1);
    }
}

// ---------------- scan stage 1 ----------------
__global__ void k_scan1(const int* __restrict__ deg, int* __restrict__ off,
                        int* __restrict__ bs, int nNodes) {
    __shared__ int tmp[256];
    int t = threadIdx.x;
    int i = blockIdx.x * 256 + t;
    int v = (i < nNodes) ? deg[i] : 0;
    tmp[t] = v;
    __syncthreads();
    for (int d = 1; d < 256; d <<= 1) {
        int add = (t >= d) ? tmp[t - d] : 0;
        __syncthreads();
        tmp[t] += add;
        __syncthreads();
    }
    if (i < nNodes) off[i] = tmp[t] - v;
    if (t == 255) bs[blockIdx.x] = tmp[255];
}

// ---------------- scan stage 2 (1 block) ----------------
__global__ void k_scan2(int* __restrict__ bs, int nb) {
    __shared__ int tmp[512];
    int t = threadIdx.x;
    int carry = 0;
    for (int start = 0; start < nb; start += 512) {
        int i = start + t;
        int v = (i < nb) ? bs[i] : 0;
        tmp[t] = v;
        __syncthreads();
        for (int d = 1; d < 512; d <<= 1) {
            int add = (t >= d) ? tmp[t - d] : 0;
            __syncthreads();
            tmp[t] += add;
            __syncthreads();
        }
        int incl = tmp[t];
        if (i < nb) bs[i] = incl - v + carry;
        int total = tmp[511];
        __syncthreads();
        carry += total;
    }
}

// ---------------- scan stage 3 ----------------
__global__ void k_scan3(int* __restrict__ off, const int* __restrict__ bs, int nNodes) {
    int i = blockIdx.x * 256 + threadIdx.x;
    if (i < nNodes) off[i] += bs[blockIdx.x];
}

// ---------------- CSR fill ----------------
__global__ void k_fill(const int* __restrict__ src, const int* __restrict__ dst,
                       const int* __restrict__ off, int* __restrict__ cur,
                       int* __restrict__ adj, int E, int nNodes) {
    int i = blockIdx.x * blockDim.x + threadIdx.x;
    if (i < E) {
        unsigned d = (unsigned)dst[i];
        unsigned s = (unsigned)src[i];
        if (d < (unsigned)nNodes && s < (unsigned)nNodes) {
            int pos = atomicAdd(&cur[d], 1);
            adj[off[d] + pos] = (int)s;
        }
    }
}

#define ACC8(A, O, U)                                                     \
    {                                                                     \
        float2 t0 = __half22float2(u2h((U).x));                           \
        float2 t1 = __half22float2(u2h((U).y));                           \
        float2 t2 = __half22float2(u2h((U).z));                           \
        float2 t3 = __half22float2(u2h((U).w));                           \
        A[O+0] += t0.x; A[O+1] += t0.y; A[O+2] += t1.x; A[O+3] += t1.y;   \
        A[O+4] += t2.x; A[O+5] += t2.y; A[O+6] += t3.x; A[O+7] += t3.y;   \
    }

// ---------------- per-tile gather-mean ----------------
// slice  = feat tile [N][16] fp16 (contiguous 3.2 MB -> L2-resident per XCD)
// mslice = msg  tile [N][16] fp16. 2 threads per node (even/odd neighbors),
// x4 unroll each -> 8 row-fetches in flight per pair; shfl_xor(1) combine.
__launch_bounds__(256)
__global__ void k_gath_t(const unsigned short* __restrict__ slice,
                         const int* __restrict__ adj, const int* __restrict__ off,
                         const int* __restrict__ deg,
                         unsigned short* __restrict__ mslice, int nNodes) {
    int i = blockIdx.x * 256 + threadIdx.x;
    int n = i >> 1, par = i & 1;
    if (n >= nNodes) return;
    int o0 = off[n], dg = deg[n];
    int o1 = o0 + dg;
    float a[16];
#pragma unroll
    for (int j = 0; j < 16; ++j) a[j] = 0.f;
    const uint4* f4 = (const uint4*)slice;       // row = 2 uint4 (32 B)

    int k = o0 + par;
    for (; k + 6 < o1; k += 8) {                 // 4 neighbors per thread per iter
        int s0 = __builtin_nontemporal_load(&adj[k + 0]);
        int s1 = __builtin_nontemporal_load(&adj[k + 2]);
        int s2 = __builtin_nontemporal_load(&adj[k + 4]);
        int s3 = __builtin_nontemporal_load(&adj[k + 6]);
        uint4 p0 = f4[2 * (long long)s0], q0 = f4[2 * (long long)s0 + 1];
        uint4 p1 = f4[2 * (long long)s1], q1 = f4[2 * (long long)s1 + 1];
        uint4 p2 = f4[2 * (long long)s2], q2 = f4[2 * (long long)s2 + 1];
        uint4 p3 = f4[2 * (long long)s3], q3 = f4[2 * (long long)s3 + 1];
        ACC8(a, 0, p0) ACC8(a, 8, q0)
        ACC8(a, 0, p1) ACC8(a, 8, q1)
        ACC8(a, 0, p2) ACC8(a, 8, q2)
        ACC8(a, 0, p3) ACC8(a, 8, q3)
    }
    for (; k < o1; k += 2) {
        int s = __builtin_nontemporal_load(&adj[k]);
        uint4 p = f4[2 * (long long)s], q = f4[2 * (long long)s + 1];
        ACC8(a, 0, p) ACC8(a, 8, q)
    }
#pragma unroll
    for (int j = 0; j < 16; ++j) a[j] += __shfl_xor(a[j], 1);
    if (par == 0) {
        float inv = 1.f / fmaxf((float)dg, 1.f);
        unsigned s0 = h2u(__floats2half2_rn(a[0] * inv,  a[1] * inv));
        unsigned s1 = h2u(__floats2half2_rn(a[2] * inv,  a[3] * inv));
        unsigned s2 = h2u(__floats2half2_rn(a[4] * inv,  a[5] * inv));
        unsigned s3 = h2u(__floats2half2_rn(a[6] * inv,  a[7] * inv));
        unsigned s4 = h2u(__floats2half2_rn(a[8] * inv,  a[9] * inv));
        unsigned s5 = h2u(__floats2half2_rn(a[10] * inv, a[11] * inv));
        unsigned s6 = h2u(__floats2half2_rn(a[12] * inv, a[13] * inv));
        unsigned s7 = h2u(__floats2half2_rn(a[14] * inv, a[15] * inv));
        unsigned* mp = (unsigned*)mslice + (long long)n * 8;
        __builtin_nontemporal_store(s0, mp + 0);
        __builtin_nontemporal_store(s1, mp + 1);
        __builtin_nontemporal_store(s2, mp + 2);
        __builtin_nontemporal_store(s3, mp + 3);
        __builtin_nontemporal_store(s4, mp + 4);
        __builtin_nontemporal_store(s5, mp + 5);
        __builtin_nontemporal_store(s6, mp + 6);
        __builtin_nontemporal_store(s7, mp + 7);
    }
}

// per-j FMA step macro: J = k within granule, COMP = float4 component
#define SAGE_STEP(J, COMP, WR4, WL4, RSTRIDE)                             \
    {                                                                     \
        float4 wr4 = WR4[(kc * 4 + J) * RSTRIDE + cg];                    \
        float4 wl4 = WL4[(kc * 4 + J) * RSTRIDE + cg];                    \
        _Pragma("unroll")                                                 \
        for (int rr = 0; rr < NROWS; ++rr) {                              \
            float xvj = xv[rr].COMP, mvj = mv[rr].COMP;                   \
            acc[rr][0] += xvj * wr4.x + mvj * wl4.x;                      \
            acc[rr][1] += xvj * wr4.y + mvj * wl4.y;                      \
            acc[rr][2] += xvj * wr4.z + mvj * wl4.z;                      \
            acc[rr][3] += xvj * wr4.w + mvj * wl4.w;                      \
        }                                                                 \
    }

// stage ms[32][PITCH] from tiled fp16 msg (coalesced uint4 reads)
#define STAGE_MS(PITCH)                                                   \
    for (int i = tid; i < 512; i += 256) {                                \
        int t = i >> 6, j = i & 63;                                       \
        int row = j >> 1, c = j & 1;                                      \
        int n = base + row;                                               \
        uint4 v = make_uint4(0u, 0u, 0u, 0u);                             \
        if (n < nNodes) v = ((const uint4*)msg)[((long long)t * nNodes + n) * 2 + c]; \
        float2 f0 = __half22float2(u2h(v.x)), f1 = __half22float2(u2h(v.y)); \
        float2 f2 = __half22float2(u2h(v.z)), f3 = __half22float2(u2h(v.w)); \
        ((float4*)&ms[row][0])[t * 4 + c * 2 + 0] = make_float4(f0.x, f0.y, f1.x, f1.y); \
        ((float4*)&ms[row][0])[t * 4 + c * 2 + 1] = make_float4(f2.x, f2.y, f3.x, f3.y); \
    }

// ---------------- SAGE layer 1 dense: hb(tiled) = relu(ms@Wl^T + b + x@Wr^T) ----------------
__launch_bounds__(256)
__global__ void k_sage1(const float* __restrict__ x, const unsigned short* __restrict__ msg,
                        const float* __restrict__ Wtl, const float* __restrict__ bl,
                        const float* __restrict__ Wtr,
                        unsigned* __restrict__ hb, int nNodes) {
    __shared__ float xs[32][128];
    __shared__ float ms[32][128];
    int tid = threadIdx.x;
    int base = blockIdx.x * 32;

    for (int i = tid; i < 32 * 32; i += 256) {
        int row = i >> 5, col4 = i & 31;
        int n = base + row;
        float4 xv = make_float4(0.f, 0.f, 0.f, 0.f);
        if (n < nNodes) xv = ((const float4*)x)[(long long)n * 32 + col4];
        ((float4*)&xs[row][0])[col4] = xv;
    }
    STAGE_MS(128)
    __syncthreads();

    const int NROWS = 4;
    int cg = tid & 31;
    int rg = tid >> 5;
    float acc[4][4];
#pragma unroll
    for (int rr = 0; rr < 4; ++rr)
#pragma unroll
        for (int cc = 0; cc < 4; ++cc) acc[rr][cc] = 0.f;

    const float4* WtR4 = (const float4*)Wtr;
    const float4* WtL4 = (const float4*)Wtl;

    for (int kc = 0; kc < 32; ++kc) {
        float4 xv[4], mv[4];
#pragma unroll
        for (int rr = 0; rr < 4; ++rr) {
            xv[rr] = ((const float4*)&xs[rg * 4 + rr][0])[kc];
            mv[rr] = ((const float4*)&ms[rg * 4 + rr][0])[kc];
        }
        SAGE_STEP(0, x, WtR4, WtL4, 32)
        SAGE_STEP(1, y, WtR4, WtL4, 32)
        SAGE_STEP(2, z, WtR4, WtL4, 32)
        SAGE_STEP(3, w, WtR4, WtL4, 32)
    }

    float4 b4 = ((const float4*)bl)[cg];
    int t = cg >> 2;                   // output tile of channels 4cg..4cg+3
#pragma unroll
    for (int rr = 0; rr < 4; ++rr) {
        int n = base + rg * 4 + rr;
        if (n < nNodes) {
            float r0 = fmaxf(acc[rr][0] + b4.x, 0.f);
            float r1 = fmaxf(acc[rr][1] + b4.y, 0.f);
            float r2 = fmaxf(acc[rr][2] + b4.z, 0.f);
            float r3 = fmaxf(acc[rr][3] + b4.w, 0.f);
            uint2 st;
            st.x = h2u(__floats2half2_rn(r0, r1));
            st.y = h2u(__floats2half2_rn(r2, r3));
            ((uint2*)hb)[((long long)t * nNodes + n) * 4 + (cg & 3)] = st;
        }
    }
}

// ---------------- SAGE layer 2 dense (64 out ch, no relu); self-tile from tiled hb ----------------
__launch_bounds__(256)
__global__ void k_sage2(const unsigned short* __restrict__ hb,
                        const unsigned short* __restrict__ msg,
                        const float* __restrict__ Wtl, const float* __restrict__ bl,
                        const float* __restrict__ Wtr,
                        float* __restrict__ z, int nNodes) {
    __shared__ float xs[32][132];
    __shared__ float ms[32][132];
    int tid = threadIdx.x;
    int base = blockIdx.x * 32;

    for (int i = tid; i < 32 * 32; i += 256) {
        int row = i >> 5, col4 = i & 31;
        int n = base + row;
        float4 xv = make_float4(0.f, 0.f, 0.f, 0.f);
        if (n < nNodes) {
            int t = col4 >> 2;
            uint2 v = ((const uint2*)hb)[((long long)t * nNodes + n) * 4 + (col4 & 3)];
            float2 f0 = __half22float2(u2h(v.x));
            float2 f1 = __half22float2(u2h(v.y));
            xv = make_float4(f0.x, f0.y, f1.x, f1.y);
        }
        ((float4*)&xs[row][0])[col4] = xv;
    }
    STAGE_MS(132)
    __syncthreads();

    const int NROWS = 2;
    int cg = tid & 15;
    int rg = tid >> 4;
    float acc[2][4];
#pragma unroll
    for (int rr = 0; rr < 2; ++rr)
#pragma unroll
        for (int cc = 0; cc < 4; ++cc) acc[rr][cc] = 0.f;

    const float4* WtR4 = (const float4*)Wtr;
    const float4* WtL4 = (const float4*)Wtl;

    for (int kc = 0; kc < 32; ++kc) {
        float4 xv[2], mv[2];
#pragma unroll
        for (int rr = 0; rr < 2; ++rr) {
            xv[rr] = ((const float4*)&xs[rg * 2 + rr][0])[kc];
            mv[rr] = ((const float4*)&ms[rg * 2 + rr][0])[kc];
        }
        SAGE_STEP(0, x, WtR4, WtL4, 16)
        SAGE_STEP(1, y, WtR4, WtL4, 16)
        SAGE_STEP(2, z, WtR4, WtL4, 16)
        SAGE_STEP(3, w, WtR4, WtL4, 16)
    }

    float4 b4 = ((const float4*)bl)[cg];
#pragma unroll
    for (int rr = 0; rr < 2; ++rr) {
        int n = base + rg * 2 + rr;
        if (n < nNodes) {
            float4 o;
            o.x = acc[rr][0] + b4.x;
            o.y = acc[rr][1] + b4.y;
            o.z = acc[rr][2] + b4.z;
            o.w = acc[rr][3] + b4.w;
            ((float4*)z)[(long long)n * 16 + cg] = o;
        }
    }
}

// ---------------- decoder: out = z @ W_dec^T + b_dec ----------------
__launch_bounds__(256)
__global__ void k_dec(const float* __restrict__ z, const float* __restrict__ Wt,
                      const float* __restrict__ b,
                      float* __restrict__ out, int nNodes) {
    __shared__ float zs[32][64];
    int tid = threadIdx.x;
    int base = blockIdx.x * 32;

    for (int i = tid; i < 32 * 16; i += 256) {
        int row = i >> 4, col4 = i & 15;
        int n = base + row;
        float4 zv = make_float4(0.f, 0.f, 0.f, 0.f);
        if (n < nNodes) zv = ((const float4*)z)[(long long)n * 16 + col4];
        ((float4*)&zs[row][0])[col4] = zv;
    }
    __syncthreads();

    int cg = tid & 31;
    int rg = tid >> 5;
    float acc[4][4];
#pragma unroll
    for (int rr = 0; rr < 4; ++rr)
#pragma unroll
        for (int cc = 0; cc < 4; ++cc) acc[rr][cc] = 0.f;

    const float4* Wt4 = (const float4*)Wt;

    for (int kc = 0; kc < 16; ++kc) {
        float4 zv[4];
#pragma unroll
        for (int rr = 0; rr < 4; ++rr)
            zv[rr] = ((const float4*)&zs[rg * 4 + rr][0])[kc];
#define DEC_STEP(J, COMP)                                                  \
        {                                                                  \
            float4 w4 = Wt4[(kc * 4 + J) * 32 + cg];                       \
            _Pragma("unroll")                                              \
            for (int rr = 0; rr < 4; ++rr) {                               \
                float zj = zv[rr].COMP;                                    \
                acc[rr][0] += zj * w4.x;                                   \
                acc[rr][1] += zj * w4.y;                                   \
                acc[rr][2] += zj * w4.z;                                   \
                acc[rr][3] += zj * w4.w;                                   \
            }                                                              \
        }
        DEC_STEP(0, x)
        DEC_STEP(1, y)
        DEC_STEP(2, z)
        DEC_STEP(3, w)
#undef DEC_STEP
    }

    float4 b4 = ((const float4*)b)[cg];
#pragma unroll
    for (int rr = 0; rr < 4; ++rr) {
        int n = base + rg * 4 + rr;
        if (n < nNodes) {
            float4 o;
            o.x = acc[rr][0] + b4.x;
            o.y = acc[rr][1] + b4.y;
            o.z = acc[rr][2] + b4.z;
            o.w = acc[rr][3] + b4.w;
            ((float4*)out)[(long long)n * 32 + cg] = o;
        }
    }
}

extern "C" void kernel_launch(void* const* d_in, const int* in_sizes, int n_in,
                              void* d_out, int out_size, void* d_ws, size_t ws_size,
                              hipStream_t stream) {
    const float* x    = (const float*)d_in[0];
    const int*   ei   = (const int*)d_in[1];   // int32 on device
    const float* W1l  = (const float*)d_in[2];
    const float* b1l  = (const float*)d_in[3];
    const float* W1r  = (const float*)d_in[4];
    const float* W2l  = (const float*)d_in[5];
    const float* b2l  = (const float*)d_in[6];
    const float* W2r  = (const float*)d_in[7];
    const float* Wdec = (const float*)d_in[8];
    const float* bdec = (const float*)d_in[9];

    const int N = in_sizes[0] / 128;
    const int E = in_sizes[1] / 2;
    const int nb = (N + 255) / 256;

    const int* src = ei;
    const int* dst = ei + E;

    // ws: [float Wt: wt1l 16384 | wt1r 16384 | wt2l 8192 | wt2r 8192 | wtdec 8192]
    //     [int: adj E | deg N | cur N | off N | bs nb] [fp16 msg: 8*N*16]
    float* wsf   = (float*)d_ws;
    float* wt1l  = wsf;
    float* wt1r  = wt1l + 16384;
    float* wt2l  = wt1r + 16384;
    float* wt2r  = wt2l + 8192;
    float* wtdec = wt2r + 8192;
    int*   adj   = (int*)(wtdec + 8192);
    int*   deg   = adj + E;
    int*   cur   = deg + N;
    int*   off   = cur + N;
    int*   bs    = off + N;
    unsigned short* msg = (unsigned short*)(bs + nb);
    msg = (unsigned short*)(((size_t)msg + 15) & ~(size_t)15);

    // d_out: x_recon [N*128 f32] | z [N*64 f32]. fp16 TILED tensors parked in
    // the x_recon region (decoder overwrites it last):
    //   xt = fp16 tiled x: first N*64 floats; hb = fp16 tiled h: next N*64.
    float*          outp = (float*)d_out;
    float*          z    = outp + (long long)N * 128;
    float*          xrec = outp;
    unsigned short* xt   = (unsigned short*)outp;
    unsigned*       hbW  = (unsigned*)(outp + (long long)N * 64);
    unsigned short* hb   = (unsigned short*)hbW;

    const int nblk = (N + 31) / 32;

    k_tw5  <<<(57344 + 255) / 256, 256, 0, stream>>>(W1l, W1r, W2l, W2r, Wdec,
                                                     wt1l, wt1r, wt2l, wt2r, wtdec);
    k_cvt_t<<<nblk, 256, 0, stream>>>(x, xt, N);

    hipMemsetAsync(deg, 0, (size_t)2 * N * sizeof(int), stream);

    k_deg  <<<(E + 255) / 256, 256, 0, stream>>>(dst, deg, E, N);
    k_scan1<<<nb, 256, 0, stream>>>(deg, off, bs, N);
    k_scan2<<<1, 512, 0, stream>>>(bs, nb);
    k_scan3<<<nb, 256, 0, stream>>>(off, bs, N);
    k_fill <<<(E + 255) / 256, 256, 0, stream>>>(src, dst, off, cur, adj, E, N);

    const int gblk = (2 * N + 255) / 256;

    // layer 1: 8 serialized per-tile gathers (xt slice L2-resident), then dense
    for (int t = 0; t < 8; ++t)
        k_gath_t<<<gblk, 256, 0, stream>>>(xt + (size_t)t * N * 16, adj, off, deg,
                                           msg + (size_t)t * N * 16, N);
    k_sage1<<<nblk, 256, 0, stream>>>(x, msg, wt1l, b1l, wt1r, hbW, N);

    // layer 2: same over tiled hb
    for (int t = 0; t < 8; ++t)
        k_gath_t<<<gblk, 256, 0, stream>>>(hb + (size_t)t * N * 16, adj, off, deg,
                                           msg + (size_t)t * N * 16, N);
    k_sage2<<<nblk, 256, 0, stream>>>(hb, msg, wt2l, b2l, wt2r, z, N);

    k_dec  <<<nblk, 256, 0, stream>>>(z, Wdec == nullptr ? wtdec : wtdec, bdec, xrec, N);
}

// Round 14
// 355.985 us; speedup vs baseline: 2.6875x; 2.5693x over previous
//
#include <hip/hip_runtime.h>
#include <hip/hip_fp16.h>

// N = 100000, E = 1600000, IN=128, HID=128, LAT=64. edge_index = int32 on device.
//
// R10 base (fused fp16 gather, CSR counting-sort) + MFMA dense phases:
// f16 16x16x32 MFMA with f32 accumulation; weights pre-packed in B-fragment
// order (fp16); LDS activation tiles fp16, rows padded +8 (bank-alias 2-way).

typedef _Float16 half8_t __attribute__((ext_vector_type(8)));
typedef float f32x4 __attribute__((ext_vector_type(4)));
union U4H8 { uint4 u; half8_t h; };

__device__ __forceinline__ unsigned h2u(__half2 h) { union { __half2 h; unsigned u; } c; c.h = h; return c.u; }
__device__ __forceinline__ __half2 u2h(unsigned u) { union { unsigned u; __half2 h; } c; c.u = u; return c.h; }

// ---------------- f32 -> fp16 convert (x4) ----------------
__global__ void k_cvt(const float* __restrict__ in, unsigned* __restrict__ ob, int n4) {
    int i = blockIdx.x * blockDim.x + threadIdx.x;
    if (i < n4) {
        float4 v = ((const float4*)in)[i];
        uint2 o;
        o.x = h2u(__floats2half2_rn(v.x, v.y));
        o.y = h2u(__floats2half2_rn(v.z, v.w));
        ((uint2*)ob)[i] = o;
    }
}

// ---------------- weight prep: fp16 B-fragment order ----------------
// frag idx = ((kc*NT + tn)*64 + lane)*8 + j ; value = W[tn*16+(lane&15)][kc*32+(lane>>4)*8+j]
__device__ __forceinline__ void wseg(const float* __restrict__ W, _Float16* __restrict__ out,
                                     int j, int K, int NT) {
    int kcs = NT * 512;
    int kc = j / kcs, r = j % kcs;
    int tn = r / 512; r = r % 512;
    int lane = r / 8, jj = r % 8;
    int oc = tn * 16 + (lane & 15);
    int k  = kc * 32 + (lane >> 4) * 8 + jj;
    out[j] = (_Float16)W[oc * K + k];
}

__global__ void k_wprep(const float* __restrict__ W1l, const float* __restrict__ W1r,
                        const float* __restrict__ W2l, const float* __restrict__ W2r,
                        const float* __restrict__ Wdec, _Float16* __restrict__ wf) {
    int i = blockIdx.x * blockDim.x + threadIdx.x;  // 0..57343
    if (i < 16384)      wseg(W1r, wf,          i,          128, 8);
    else if (i < 32768) wseg(W1l, wf + 16384,  i - 16384,  128, 8);
    else if (i < 40960) wseg(W2r, wf + 32768,  i - 32768,  128, 4);
    else if (i < 49152) wseg(W2l, wf + 40960,  i - 40960,  128, 4);
    else if (i < 57344) wseg(Wdec, wf + 49152, i - 49152,  64,  8);
}

// ---------------- degree ----------------
__global__ void k_deg(const int* __restrict__ dst, int* __restrict__ deg, int E, int nNodes) {
    int i = blockIdx.x * blockDim.x + threadIdx.x;
    if (i < E) {
        unsigned d = (unsigned)dst[i];
        if (d < (unsigned)nNodes) atomicAdd(&deg[d], 1);
    }
}

// ---------------- scans ----------------
__global__ void k_scan1(const int* __restrict__ deg, int* __restrict__ off,
                        int* __restrict__ bs, int nNodes) {
    __shared__ int tmp[256];
    int t = threadIdx.x;
    int i = blockIdx.x * 256 + t;
    int v = (i < nNodes) ? deg[i] : 0;
    tmp[t] = v;
    __syncthreads();
    for (int d = 1; d < 256; d <<= 1) {
        int add = (t >= d) ? tmp[t - d] : 0;
        __syncthreads();
        tmp[t] += add;
        __syncthreads();
    }
    if (i < nNodes) off[i] = tmp[t] - v;
    if (t == 255) bs[blockIdx.x] = tmp[255];
}

__global__ void k_scan2(int* __restrict__ bs, int nb) {
    __shared__ int tmp[512];
    int t = threadIdx.x;
    int carry = 0;
    for (int start = 0; start < nb; start += 512) {
        int i = start + t;
        int v = (i < nb) ? bs[i] : 0;
        tmp[t] = v;
        __syncthreads();
        for (int d = 1; d < 512; d <<= 1) {
            int add = (t >= d) ? tmp[t - d] : 0;
            __syncthreads();
            tmp[t] += add;
            __syncthreads();
        }
        int incl = tmp[t];
        if (i < nb) bs[i] = incl - v + carry;
        int total = tmp[511];
        __syncthreads();
        carry += total;
    }
}

__global__ void k_scan3(int* __restrict__ off, const int* __restrict__ bs, int nNodes) {
    int i = blockIdx.x * 256 + threadIdx.x;
    if (i < nNodes) off[i] += bs[blockIdx.x];
}

// ---------------- CSR fill ----------------
__global__ void k_fill(const int* __restrict__ src, const int* __restrict__ dst,
                       const int* __restrict__ off, int* __restrict__ cur,
                       int* __restrict__ adj, int E, int nNodes) {
    int i = blockIdx.x * blockDim.x + threadIdx.x;
    if (i < E) {
        unsigned d = (unsigned)dst[i];
        unsigned s = (unsigned)src[i];
        if (d < (unsigned)nNodes && s < (unsigned)nNodes) {
            int pos = atomicAdd(&cur[d], 1);
            adj[off[d] + pos] = (int)s;
        }
    }
}

// ---------------- fp16 gather-mean into LDS tile (R10 structure) ----------------
// Wave w: rows w*8..w*8+7. q=(lane>>4)&3 takes neighbors k=o0+q step4; lq=lane&15
// holds 8 ch as uint4. __hadd2 accumulate; f32 cross-quarter reduce; fp16 store.
__device__ __forceinline__ void gather_ms(const unsigned short* __restrict__ feat,
                                          const int* __restrict__ adj,
                                          const int* __restrict__ off,
                                          const int* __restrict__ deg,
                                          unsigned short (*ms)[136],
                                          int base, int nNodes, int tid) {
    int w = tid >> 6, lane = tid & 63;
    int q = (lane >> 4) & 3, lq = lane & 15;
    const uint4* feat4 = (const uint4*)feat;   // fp16 row = 16 uint4
    for (int r = w * 8; r < w * 8 + 8; ++r) {
        int n = base + r;
        __half2 zero = __floats2half2_rn(0.f, 0.f);
        __half2 acc2[4] = {zero, zero, zero, zero};
        float inv = 1.f;
        if (n < nNodes) {
            int o0 = off[n];
            int dg = deg[n];
            int o1 = o0 + dg;
            int kb = o0;
            for (; kb + 15 < o1; kb += 16) {
                int s0 = adj[kb + q];
                int s1 = adj[kb + q + 4];
                int s2 = adj[kb + q + 8];
                int s3 = adj[kb + q + 12];
                uint4 f0 = feat4[(long long)s0 * 16 + lq];
                uint4 f1 = feat4[(long long)s1 * 16 + lq];
                uint4 f2 = feat4[(long long)s2 * 16 + lq];
                uint4 f3 = feat4[(long long)s3 * 16 + lq];
                acc2[0] = __hadd2(acc2[0], __hadd2(__hadd2(u2h(f0.x), u2h(f1.x)),
                                                  __hadd2(u2h(f2.x), u2h(f3.x))));
                acc2[1] = __hadd2(acc2[1], __hadd2(__hadd2(u2h(f0.y), u2h(f1.y)),
                                                  __hadd2(u2h(f2.y), u2h(f3.y))));
                acc2[2] = __hadd2(acc2[2], __hadd2(__hadd2(u2h(f0.z), u2h(f1.z)),
                                                  __hadd2(u2h(f2.z), u2h(f3.z))));
                acc2[3] = __hadd2(acc2[3], __hadd2(__hadd2(u2h(f0.w), u2h(f1.w)),
                                                  __hadd2(u2h(f2.w), u2h(f3.w))));
            }
            for (int k = kb + q; k < o1; k += 4) {
                uint4 f = feat4[(long long)adj[k] * 16 + lq];
                acc2[0] = __hadd2(acc2[0], u2h(f.x));
                acc2[1] = __hadd2(acc2[1], u2h(f.y));
                acc2[2] = __hadd2(acc2[2], u2h(f.z));
                acc2[3] = __hadd2(acc2[3], u2h(f.w));
            }
            inv = 1.f / fmaxf((float)dg, 1.f);
        }
        float a[8];
#pragma unroll
        for (int j = 0; j < 4; ++j) {
            float2 f = __half22float2(acc2[j]);
            a[2 * j] = f.x; a[2 * j + 1] = f.y;
        }
#pragma unroll
        for (int j = 0; j < 8; ++j) {
            a[j] += __shfl_xor(a[j], 16);
            a[j] += __shfl_xor(a[j], 32);
        }
        if (q == 0) {
            uint4 st;
            st.x = h2u(__floats2half2_rn(a[0] * inv, a[1] * inv));
            st.y = h2u(__floats2half2_rn(a[2] * inv, a[3] * inv));
            st.z = h2u(__floats2half2_rn(a[4] * inv, a[5] * inv));
            st.w = h2u(__floats2half2_rn(a[6] * inv, a[7] * inv));
            *(uint4*)&ms[r][lq * 8] = st;
        }
    }
}

// stage a [32][128] fp16 tile from flat fp16 feature matrix
#define STAGE_XS(FEAT)                                                    \
    for (int i = tid; i < 512; i += 256) {                                \
        int row = i >> 4, c = i & 15;                                     \
        int n = base + row;                                               \
        uint4 v = make_uint4(0u, 0u, 0u, 0u);                             \
        if (n < nNodes) v = ((const uint4*)(FEAT))[(long long)n * 16 + c];\
        *(uint4*)&xs[row][c * 8] = v;                                     \
    }

// ---------------- SAGE layer 1: gather + MFMA dense, h (fp16) out ----------------
__launch_bounds__(256)
__global__ void k_sage1(const unsigned short* __restrict__ xh,
                        const int* __restrict__ adj, const int* __restrict__ off,
                        const int* __restrict__ deg,
                        const _Float16* __restrict__ wfr, const _Float16* __restrict__ wfl,
                        const float* __restrict__ bl,
                        unsigned short* __restrict__ hb, int nNodes) {
    __shared__ unsigned short xs[32][136];
    __shared__ unsigned short ms[32][136];
    int tid = threadIdx.x;
    int base = blockIdx.x * 32;

    STAGE_XS(xh)
    gather_ms(xh, adj, off, deg, ms, base, nNodes, tid);
    __syncthreads();

    int w = tid >> 6, lane = tid & 63;
    int tm = w >> 1, tnb = (w & 1) * 4;        // wave: M-tile tm, N-tiles tnb..tnb+3
    int arow = tm * 16 + (lane & 15);
    int kofs = (lane >> 4) * 8;
    f32x4 acc[4];
#pragma unroll
    for (int t = 0; t < 4; ++t) acc[t] = (f32x4){0.f, 0.f, 0.f, 0.f};

    const uint4* WR = (const uint4*)wfr;
    const uint4* WL = (const uint4*)wfl;
#pragma unroll
    for (int kc = 0; kc < 4; ++kc) {
        U4H8 ax, am;
        ax.u = *(const uint4*)&xs[arow][kc * 32 + kofs];
        am.u = *(const uint4*)&ms[arow][kc * 32 + kofs];
#pragma unroll
        for (int t = 0; t < 4; ++t) {
            U4H8 br, blf;
            br.u  = WR[(kc * 8 + tnb + t) * 64 + lane];
            blf.u = WL[(kc * 8 + tnb + t) * 64 + lane];
            acc[t] = __builtin_amdgcn_mfma_f32_16x16x32_f16(ax.h, br.h,  acc[t], 0, 0, 0);
            acc[t] = __builtin_amdgcn_mfma_f32_16x16x32_f16(am.h, blf.h, acc[t], 0, 0, 0);
        }
    }

    int col = lane & 15, rb = (lane >> 4) * 4;
#pragma unroll
    for (int t = 0; t < 4; ++t) {
        int ch = (tnb + t) * 16 + col;
        float bias = bl[ch];
#pragma unroll
        for (int r = 0; r < 4; ++r) {
            int node = base + tm * 16 + rb + r;
            if (node < nNodes) {
                _Float16 hv = (_Float16)fmaxf(acc[t][r] + bias, 0.f);
                hb[(long long)node * 128 + ch] = __builtin_bit_cast(unsigned short, hv);
            }
        }
    }
}

// ---------------- SAGE layer 2: gather + MFMA dense, z (f32) + zh (fp16) ----------------
__launch_bounds__(256)
__global__ void k_sage2(const unsigned short* __restrict__ hb,
                        const int* __restrict__ adj, const int* __restrict__ off,
                        const int* __restrict__ deg,
                        const _Float16* __restrict__ wfr, const _Float16* __restrict__ wfl,
                        const float* __restrict__ bl,
                        float* __restrict__ z, unsigned short* __restrict__ zh, int nNodes) {
    __shared__ unsigned short xs[32][136];
    __shared__ unsigned short ms[32][136];
    int tid = threadIdx.x;
    int base = blockIdx.x * 32;

    STAGE_XS(hb)
    gather_ms(hb, adj, off, deg, ms, base, nNodes, tid);
    __syncthreads();

    int w = tid >> 6, lane = tid & 63;
    int tm = w >> 1, tnb = (w & 1) * 2;        // N-tiles: 4 total (64 ch)
    int arow = tm * 16 + (lane & 15);
    int kofs = (lane >> 4) * 8;
    f32x4 acc[2];
#pragma unroll
    for (int t = 0; t < 2; ++t) acc[t] = (f32x4){0.f, 0.f, 0.f, 0.f};

    const uint4* WR = (const uint4*)wfr;
    const uint4* WL = (const uint4*)wfl;
#pragma unroll
    for (int kc = 0; kc < 4; ++kc) {
        U4H8 ax, am;
        ax.u = *(const uint4*)&xs[arow][kc * 32 + kofs];
        am.u = *(const uint4*)&ms[arow][kc * 32 + kofs];
#pragma unroll
        for (int t = 0; t < 2; ++t) {
            U4H8 br, blf;
            br.u  = WR[(kc * 4 + tnb + t) * 64 + lane];
            blf.u = WL[(kc * 4 + tnb + t) * 64 + lane];
            acc[t] = __builtin_amdgcn_mfma_f32_16x16x32_f16(ax.h, br.h,  acc[t], 0, 0, 0);
            acc[t] = __builtin_amdgcn_mfma_f32_16x16x32_f16(am.h, blf.h, acc[t], 0, 0, 0);
        }
    }

    int col = lane & 15, rb = (lane >> 4) * 4;
#pragma unroll
    for (int t = 0; t < 2; ++t) {
        int ch = (tnb + t) * 16 + col;
        float bias = bl[ch];
#pragma unroll
        for (int r = 0; r < 4; ++r) {
            int node = base + tm * 16 + rb + r;
            if (node < nNodes) {
                float v = acc[t][r] + bias;
                z[(long long)node * 64 + ch] = v;
                _Float16 hv = (_Float16)v;
                zh[(long long)node * 64 + ch] = __builtin_bit_cast(unsigned short, hv);
            }
        }
    }
}

// ---------------- decoder: MFMA, out = zh @ Wdec^T + b ----------------
__launch_bounds__(256)
__global__ void k_dec(const unsigned short* __restrict__ zh,
                      const _Float16* __restrict__ wfd, const float* __restrict__ b,
                      float* __restrict__ out, int nNodes) {
    __shared__ unsigned short zs[32][72];
    int tid = threadIdx.x;
    int base = blockIdx.x * 32;

    for (int i = tid; i < 256; i += 256) {}    // (no-op placeholder removed below)
    for (int i = tid; i < 256; i += 256) {
        int row = i >> 3, c = i & 7;           // 8 uint4 per 64-ch row
        int n = base + row;
        uint4 v = make_uint4(0u, 0u, 0u, 0u);
        if (n < nNodes) v = ((const uint4*)zh)[(long long)n * 8 + c];
        *(uint4*)&zs[row][c * 8] = v;
    }
    __syncthreads();

    int w = tid >> 6, lane = tid & 63;
    int tm = w >> 1, tnb = (w & 1) * 4;        // N-tiles: 8 (128 ch)
    int arow = tm * 16 + (lane & 15);
    int kofs = (lane >> 4) * 8;
    f32x4 acc[4];
#pragma unroll
    for (int t = 0; t < 4; ++t) acc[t] = (f32x4){0.f, 0.f, 0.f, 0.f};

    const uint4* WD = (const uint4*)wfd;
#pragma unroll
    for (int kc = 0; kc < 2; ++kc) {
        U4H8 az;
        az.u = *(const uint4*)&zs[arow][kc * 32 + kofs];
#pragma unroll
        for (int t = 0; t < 4; ++t) {
            U4H8 bw;
            bw.u = WD[(kc * 8 + tnb + t) * 64 + lane];
            acc[t] = __builtin_amdgcn_mfma_f32_16x16x32_f16(az.h, bw.h, acc[t], 0, 0, 0);
        }
    }

    int col = lane & 15, rb = (lane >> 4) * 4;
#pragma unroll
    for (int t = 0; t < 4; ++t) {
        int ch = (tnb + t) * 16 + col;
        float bias = b[ch];
#pragma unroll
        for (int r = 0; r < 4; ++r) {
            int node = base + tm * 16 + rb + r;
            if (node < nNodes)
                out[(long long)node * 128 + ch] = acc[t][r] + bias;
        }
    }
}

extern "C" void kernel_launch(void* const* d_in, const int* in_sizes, int n_in,
                              void* d_out, int out_size, void* d_ws, size_t ws_size,
                              hipStream_t stream) {
    const float* x    = (const float*)d_in[0];
    const int*   ei   = (const int*)d_in[1];   // int32 on device
    const float* W1l  = (const float*)d_in[2];
    const float* b1l  = (const float*)d_in[3];
    const float* W1r  = (const float*)d_in[4];
    const float* W2l  = (const float*)d_in[5];
    const float* b2l  = (const float*)d_in[6];
    const float* W2r  = (const float*)d_in[7];
    const float* Wdec = (const float*)d_in[8];
    const float* bdec = (const float*)d_in[9];

    const int N = in_sizes[0] / 128;
    const int E = in_sizes[1] / 2;
    const int nb = (N + 255) / 256;

    const int* src = ei;
    const int* dst = ei + E;

    // ws: [fp16 weight frags: 57344] [int: adj E | deg N | cur N | off N | bs nb]
    //     [fp16 zh: N*64]
    _Float16* wf    = (_Float16*)d_ws;
    _Float16* w1r_f = wf;
    _Float16* w1l_f = wf + 16384;
    _Float16* w2r_f = wf + 32768;
    _Float16* w2l_f = wf + 40960;
    _Float16* wdec_f= wf + 49152;
    int* adj = (int*)(wf + 57344);
    int* deg = adj + E;
    int* cur = deg + N;
    int* off = cur + N;
    int* bs  = off + N;
    unsigned short* zh = (unsigned short*)(bs + nb);
    zh = (unsigned short*)(((size_t)zh + 15) & ~(size_t)15);

    // d_out: x_recon [N*128 f32] | z [N*64 f32]. fp16 tensors parked in the
    // x_recon region (decoder overwrites it last):
    //   xh = fp16(x): first N*64 floats; hb = fp16(h): next N*64 floats.
    float*          outp = (float*)d_out;
    float*          z    = outp + (long long)N * 128;
    float*          xrec = outp;
    unsigned short* xh   = (unsigned short*)outp;
    unsigned short* hb   = (unsigned short*)(outp + (long long)N * 64);

    const int nblk = (N + 31) / 32;

    k_wprep<<<(57344 + 255) / 256, 256, 0, stream>>>(W1l, W1r, W2l, W2r, Wdec, wf);
    k_cvt  <<<(N * 32 + 255) / 256, 256, 0, stream>>>(x, (unsigned*)xh, N * 32);

    hipMemsetAsync(deg, 0, (size_t)2 * N * sizeof(int), stream);

    k_deg  <<<(E + 255) / 256, 256, 0, stream>>>(dst, deg, E, N);
    k_scan1<<<nb, 256, 0, stream>>>(deg, off, bs, N);
    k_scan2<<<1, 512, 0, stream>>>(bs, nb);
    k_scan3<<<nb, 256, 0, stream>>>(off, bs, N);
    k_fill <<<(E + 255) / 256, 256, 0, stream>>>(src, dst, off, cur, adj, E, N);

    k_sage1<<<nblk, 256, 0, stream>>>(xh, adj, off, deg, w1r_f, w1l_f, b1l, hb, N);
    k_sage2<<<nblk, 256, 0, stream>>>(hb, adj, off, deg, w2r_f, w2l_f, b2l, z, zh, N);
    k_dec  <<<nblk, 256, 0, stream>>>(zh, wdec_f, bdec, xrec, N);
}